// Round 6
// baseline (109.861 us; speedup 1.0000x reference)
//
#include <hip/hip_runtime.h>
#include <hip/hip_bf16.h>
#include <math.h>

#define NPIX 65536      // 256*256
#define SEGB 32         // segments per (b,c)
#define HEPS (6.4f / 255.0f)

typedef __bf16 bf16x8 __attribute__((ext_vector_type(8)));
typedef float  f32x4  __attribute__((ext_vector_type(4)));
typedef float  f32x2  __attribute__((ext_vector_type(2)));

__device__ __forceinline__ float clamp01(float x) { return fminf(fmaxf(x, 0.f), 1.f); }

// grid: 24*SEGB blocks, 512 threads (8 waves -> 4 waves/SIMD at 2 blocks/CU).
// Each wave computes the full 64x64 histogram for its 256 pixels via 4x4
// tiles of mfma_f32_16x16x32_bf16. Epilogue: 3-level slab tree (4 slabs,
// 5 barriers, all ds b128 conflict-free), block partial stored in
// FRAGMENT-PERMUTED layout; loss kernel un-permutes when indexing th.
// Block 0 zero-inits the 16-float control region (norms/acc/counter).
__global__ __launch_bounds__(512) void hist_mfma(const float* __restrict__ rgbd,
                                                 float* __restrict__ P,
                                                 float* __restrict__ ctrl) {
  const int blk = blockIdx.x;
  const int seg = blk & (SEGB - 1);
  const int bc  = blk / SEGB;     // 0..23
  const int b = bc / 3;
  const int c = bc - 3 * b;
  const int t = threadIdx.x;
  const int l = t & 63;
  const int w = t >> 6;           // wave 0..7

  if (blk == 0 && t < 16) ctrl[t] = 0.f;   // norms[8], acc, counter, pad

  __shared__ float stage[8][3][64];   // per-wave u50/v50/iy staging (6 KB)
  __shared__ f32x4 slab[4][16][64];   // reduction slabs, fragment layout (64 KB)

  const float* __restrict__ base = rgbd + (size_t)b * (4 * NPIX);

  f32x4 acc[16];
#pragma unroll
  for (int i = 0; i < 16; ++i) acc[i] = (f32x4){0.f, 0.f, 0.f, 0.f};

  const int halfq = l & 15;   // output col within 16-tile
  const int grp   = l >> 4;   // k-group / output row group
  const float d50_0   = (-3.f + (float)halfq * (6.f / 63.f)) * 50.f;  // delta/sigma
  const float dstep50 = (16.f * 6.f / 63.f) * 50.f;
  const f32x2 one2 = {1.f, 1.f};

  // this wave's pixels: 256, processed 64/iter
  const int p0 = seg * 2048 + w * 256;

  float pr = base[p0 + l];
  float pg = base[NPIX + p0 + l];
  float pb = base[2 * NPIX + p0 + l];

  for (int it = 0; it < 4; ++it) {
    // ---- per-pixel scalars ----
    float r  = clamp01(fmaf(pr, 0.5f, 0.5f));
    float g  = clamp01(fmaf(pg, 0.5f, 0.5f));
    float bl = clamp01(fmaf(pb, 0.5f, 0.5f));
    float iy = sqrtf(fmaf(r, r, fmaf(g, g, fmaf(bl, bl, HEPS))));
    float lr = __logf(r + HEPS);
    float lg = __logf(g + HEPS);
    float lb = __logf(bl + HEPS);
    float u, v;
    if (c == 0)      { u = lr - lg; v = lr - lb; }
    else if (c == 1) { u = lg - lr; v = lg - lb; }
    else             { u = lb - lr; v = lb - lg; }
    stage[w][0][l] = u * 50.f;     // u/sigma
    stage[w][1][l] = v * 50.f;
    stage[w][2][l] = iy;

    if (it + 1 < 4) {  // prefetch next 64 pixels
      const int p = p0 + (it + 1) * 64 + l;
      pr = base[p]; pg = base[NPIX + p]; pb = base[2 * NPIX + p];
    }
    // wave-private LDS: in-order per wave; waitcnt orders write->read
    asm volatile("s_waitcnt lgkmcnt(0)" ::: "memory");

    // ---- two K-subtiles of 32 pixels each ----
#pragma unroll
    for (int s = 0; s < 2; ++s) {
      const int k0 = s * 32 + grp * 8;   // this lane's 8 pixels
      const f32x2* __restrict__ u2  = (const f32x2*)&stage[w][0][k0];
      const f32x2* __restrict__ v2  = (const f32x2*)&stage[w][1][k0];
      const f32x2* __restrict__ iy2 = (const f32x2*)&stage[w][2][k0];

      bf16x8 af[4];
#pragma unroll
      for (int ut = 0; ut < 4; ++ut) {
        const float dlt = d50_0 + (float)ut * dstep50;
        const f32x2 dlt2 = {dlt, dlt};
#pragma unroll
        for (int jp = 0; jp < 4; ++jp) {
          f32x2 x = u2[jp] - dlt2;
          f32x2 q = x * x + one2;                 // v_pk_fma candidates
          f32x2 rc = {__builtin_amdgcn_rcpf(q[0]), __builtin_amdgcn_rcpf(q[1])};
          f32x2 a2 = iy2[jp] * rc;
          af[ut][2 * jp]     = (__bf16)a2[0];
          af[ut][2 * jp + 1] = (__bf16)a2[1];
        }
      }

#pragma unroll
      for (int vt = 0; vt < 4; ++vt) {
        const float dlt = d50_0 + (float)vt * dstep50;
        const f32x2 dlt2 = {dlt, dlt};
        bf16x8 bf;
#pragma unroll
        for (int jp = 0; jp < 4; ++jp) {
          f32x2 x = v2[jp] - dlt2;
          f32x2 q = x * x + one2;
          bf[2 * jp]     = (__bf16)__builtin_amdgcn_rcpf(q[0]);
          bf[2 * jp + 1] = (__bf16)__builtin_amdgcn_rcpf(q[1]);
        }
#pragma unroll
        for (int ut = 0; ut < 4; ++ut)
          acc[ut * 4 + vt] =
              __builtin_amdgcn_mfma_f32_16x16x32_bf16(af[ut], bf, acc[ut * 4 + vt], 0, 0, 0);
      }
    }
  }

  // ---- 3-level vectorized tree reduction over 8 waves ----
  if (w >= 4) {
#pragma unroll
    for (int i = 0; i < 16; ++i) slab[w - 4][i][l] = acc[i];
  }
  __syncthreads();
  if (w < 4) {
#pragma unroll
    for (int i = 0; i < 16; ++i) acc[i] += slab[w][i][l];
  }
  __syncthreads();
  if (w == 2 || w == 3) {
#pragma unroll
    for (int i = 0; i < 16; ++i) slab[w - 2][i][l] = acc[i];
  }
  __syncthreads();
  if (w < 2) {
#pragma unroll
    for (int i = 0; i < 16; ++i) acc[i] += slab[w][i][l];
  }
  __syncthreads();
  if (w == 1) {
#pragma unroll
    for (int i = 0; i < 16; ++i) slab[0][i][l] = acc[i];
  }
  __syncthreads();
  if (w == 0) {
    // store block partial in fragment layout: flat f32x4 index = i*64 + l
    f32x4* __restrict__ Pv = (f32x4*)(P + (size_t)blk * 4096);
#pragma unroll
    for (int i = 0; i < 16; ++i) Pv[i * 64 + l] = acc[i] + slab[0][i][l];
  }
}

// ---- stage 2: parallel partial reduction (elementwise; layout-agnostic) ----
// grid 384 x 256: thread e = (bc, si). Sums SEGB partials in-place into the
// segment-0 slice of P and atomically accumulates per-b norm.
__global__ __launch_bounds__(256) void reduce_partials(float* __restrict__ P,
                                                       float* __restrict__ norms) {
  const int e  = blockIdx.x * 256 + threadIdx.x;   // 0..98303
  const int bc = e >> 12;
  const int si = e & 4095;
  float* __restrict__ p0 = P + (size_t)(bc * SEGB) * 4096 + si;
  float s = 0.f;
#pragma unroll
  for (int sg = 0; sg < SEGB; ++sg) s += p0[(size_t)sg * 4096];
  p0[0] = s;

  __shared__ float red[4];
  float ns = s;
#pragma unroll
  for (int off = 32; off > 0; off >>= 1) ns += __shfl_down(ns, off);
  if ((threadIdx.x & 63) == 0) red[threadIdx.x >> 6] = ns;
  __syncthreads();
  if (threadIdx.x == 0)
    atomicAdd(&norms[bc / 3], red[0] + red[1] + red[2] + red[3]);
}

// ---- stage 3: Hellinger loss + fused final (last block writes out) ----
__global__ __launch_bounds__(256) void loss_final(const float* __restrict__ P,
                                                  const float* __restrict__ norms,
                                                  const float* __restrict__ th,
                                                  float* __restrict__ acc,
                                                  unsigned* __restrict__ counter,
                                                  float* __restrict__ out) {
  float s = 0.f;
  for (int idx = blockIdx.x * 256 + threadIdx.x; idx < 8 * 12288;
       idx += gridDim.x * 256) {
    const int b  = idx / 12288;
    const int r  = idx - b * 12288;
    const int c  = r >> 12;
    const int si = r & 4095;                 // fragment-permuted storage index
    // inverse permutation: si = ((i*64 + l)<<2)|rg  ->  (row,col)
    const int rg = si & 3;
    const int q  = si >> 2;
    const int l  = q & 63;
    const int i  = q >> 6;
    const int row = (i >> 2) * 16 + (l >> 4) * 4 + rg;
    const int col = (i & 3) * 16 + (l & 15);
    const float h = P[(size_t)((b * 3 + c) * SEGB) * 4096 + si] / (norms[b] + HEPS);
    const float d = sqrtf(th[c * 4096 + row * 64 + col]) - sqrtf(h);
    s += d * d;
  }
  __shared__ float red[4];
#pragma unroll
  for (int off = 32; off > 0; off >>= 1) s += __shfl_down(s, off);
  if ((threadIdx.x & 63) == 0) red[threadIdx.x >> 6] = s;
  __syncthreads();
  if (threadIdx.x == 0) {
    atomicAdd(acc, red[0] + red[1] + red[2] + red[3]);
    __threadfence();
    const unsigned old = atomicAdd(counter, 1u);
    if (old == (unsigned)(gridDim.x - 1)) {
      const float tot = atomicAdd(acc, 0.f);   // all adds visible
      out[0] = sqrtf(tot) * 0.08838834764831845f;   // (1/sqrt(2))/B, B=8
    }
  }
}

extern "C" void kernel_launch(void* const* d_in, const int* in_sizes, int n_in,
                              void* d_out, int out_size, void* d_ws, size_t ws_size,
                              hipStream_t stream) {
  const float* rgbd = (const float*)d_in[0];   // [8,4,256,256]
  const float* th   = (const float*)d_in[1];   // [3,64,64]
  float* out = (float*)d_out;

  const size_t nP = (size_t)24 * SEGB * 4096;   // partial hists (12.6 MB)
  float*    P       = (float*)d_ws;
  float*    ctrl    = P + nP;                   // norms[8], acc, counter, pad
  float*    norms   = ctrl;
  float*    acc     = ctrl + 8;
  unsigned* counter = (unsigned*)(ctrl + 9);

  hist_mfma<<<24 * SEGB, 512, 0, stream>>>(rgbd, P, ctrl);
  reduce_partials<<<384, 256, 0, stream>>>(P, norms);
  loss_final<<<96, 256, 0, stream>>>(P, norms, th, acc, counter, out);
}